// Round 15
// baseline (438.617 us; speedup 1.0000x reference)
//
#include <hip/hip_runtime.h>
#include <hip/hip_bf16.h>
#include <math.h>

// Problem constants
#define L_SEQ   1024
#define DMODEL  1024
#define DINNER  2048
#define DSTATE  16
#define DCONV   4
#define NPROJ   (DINNER + 4 * DSTATE)   // 2112
#define NCHUNK  16
#define CHUNK   64                       // L_SEQ / NCHUNK
#define NDN     (DINNER * DSTATE)        // 32768 (d,n) pairs

typedef __attribute__((ext_vector_type(8))) short  short8;
typedef __attribute__((ext_vector_type(8))) unsigned short us8;
typedef __attribute__((ext_vector_type(4))) float  f32x4;
typedef __attribute__((ext_vector_type(4))) unsigned short us4;

__device__ __forceinline__ float softplus_f(float v) {
    return fmaxf(v, 0.f) + log1pf(expf(-fabsf(v)));
}
__device__ __forceinline__ float silu_f(float v) {
    return v * __builtin_amdgcn_rcpf(1.f + expf(-v));
}

// Split f32 into bf16 hi (truncated) + bf16 lo (rounded residual).
__device__ __forceinline__ void split1(float x, unsigned short& h, unsigned short& l) {
    unsigned b  = __float_as_uint(x);
    unsigned hb = b & 0xffff0000u;
    float    r  = x - __uint_as_float(hb);
    unsigned rb = __float_as_uint(r) + 0x8000u;
    h = (unsigned short)(hb >> 16);
    l = (unsigned short)(rb >> 16);
}
__device__ __forceinline__ void split4(float4 v, us4& h, us4& l) {
    float vv[4] = {v.x, v.y, v.z, v.w};
    #pragma unroll
    for (int i = 0; i < 4; ++i) {
        unsigned b  = __float_as_uint(vv[i]);
        unsigned hb = b & 0xffff0000u;
        float    r  = vv[i] - __uint_as_float(hb);
        unsigned rb = __float_as_uint(r) + 0x8000u;
        h[i] = (unsigned short)(hb >> 16);
        l[i] = (unsigned short)(rb >> 16);
    }
}

// -------- MFMA split-bf16 split-K GEMM, f32 A (runtime split both sides) --------
// Used only for GEMM1 (A = x input). Cp[kz][M][N] partials.
template<int BM>
__global__ __launch_bounds__(256) void gemm_mfma_sk(
    const float* __restrict__ A, const float* __restrict__ W,
    float* __restrict__ Cp, int M, int N, int K, int lda)
{
    constexpr int MF = BM / 32;
    constexpr int NF = 2;
    __shared__ unsigned short sAh[BM * 40], sAl[BM * 40];
    __shared__ unsigned short sBh[64 * 40], sBl[64 * 40];

    const int tid  = threadIdx.x;
    const int w    = tid >> 6;
    const int lane = tid & 63;
    const int wr   = w >> 1;
    const int wc   = w & 1;
    const int lrow = lane & 15;
    const int lkb  = lane >> 4;
    const int row0 = blockIdx.y * BM;
    const int col0 = blockIdx.x * 64;

    const int KS   = K / gridDim.z;
    const int kbeg = blockIdx.z * KS;
    const int kend = kbeg + KS;

    const int srow = tid >> 3;
    const int sfq  = tid & 7;

    f32x4 acc[MF][NF];
    #pragma unroll
    for (int m = 0; m < MF; ++m)
        #pragma unroll
        for (int n = 0; n < NF; ++n)
            acc[m][n] = (f32x4){0.f, 0.f, 0.f, 0.f};

    for (int k0 = kbeg; k0 < kend; k0 += 32) {
        #pragma unroll
        for (int p = 0; p < BM / 32; ++p) {
            int r = srow + p * 32;
            float4 v = *reinterpret_cast<const float4*>(
                A + (size_t)(row0 + r) * lda + k0 + sfq * 4);
            us4 h, l;
            split4(v, h, l);
            *reinterpret_cast<us4*>(sAh + r * 40 + sfq * 4) = h;
            *reinterpret_cast<us4*>(sAl + r * 40 + sfq * 4) = l;
        }
        #pragma unroll
        for (int p = 0; p < 2; ++p) {
            int r = srow + p * 32;
            float4 v = *reinterpret_cast<const float4*>(
                W + (size_t)(col0 + r) * K + k0 + sfq * 4);
            us4 h, l;
            split4(v, h, l);
            *reinterpret_cast<us4*>(sBh + r * 40 + sfq * 4) = h;
            *reinterpret_cast<us4*>(sBl + r * 40 + sfq * 4) = l;
        }
        __syncthreads();

        short8 ah[MF], al[MF], bh[NF], bl[NF];
        #pragma unroll
        for (int m = 0; m < MF; ++m) {
            int off = (wr * (BM / 2) + m * 16 + lrow) * 40 + lkb * 8;
            ah[m] = *reinterpret_cast<const short8*>(sAh + off);
            al[m] = *reinterpret_cast<const short8*>(sAl + off);
        }
        #pragma unroll
        for (int n = 0; n < NF; ++n) {
            int off = (wc * 32 + n * 16 + lrow) * 40 + lkb * 8;
            bh[n] = *reinterpret_cast<const short8*>(sBh + off);
            bl[n] = *reinterpret_cast<const short8*>(sBl + off);
        }

        #pragma unroll
        for (int m = 0; m < MF; ++m)
            #pragma unroll
            for (int n = 0; n < NF; ++n) {
                acc[m][n] = __builtin_amdgcn_mfma_f32_16x16x32_bf16(
                    ah[m], bh[n], acc[m][n], 0, 0, 0);
                acc[m][n] = __builtin_amdgcn_mfma_f32_16x16x32_bf16(
                    ah[m], bl[n], acc[m][n], 0, 0, 0);
                acc[m][n] = __builtin_amdgcn_mfma_f32_16x16x32_bf16(
                    al[m], bh[n], acc[m][n], 0, 0, 0);
            }
        __syncthreads();
    }

    float* Cb = Cp + (size_t)blockIdx.z * M * N;
    #pragma unroll
    for (int m = 0; m < MF; ++m)
        #pragma unroll
        for (int n = 0; n < NF; ++n) {
            int gr0 = row0 + wr * (BM / 2) + m * 16 + lkb * 4;
            int gc  = col0 + wc * 32 + n * 16 + lrow;
            #pragma unroll
            for (int r = 0; r < 4; ++r)
                Cb[(size_t)(gr0 + r) * N + gc] = acc[m][n][r];
        }
}

// -------- MFMA GEMM, pre-split bf16 A (compact [M][K] hi/lo), f32 W -------------
// A staging is pure ushort8 copy (zero split VALU). W runtime-split (8x redundant).
template<int BM>
__global__ __launch_bounds__(256) void gemm_bf16a_sk(
    const unsigned short* __restrict__ Ah, const unsigned short* __restrict__ Al,
    const float* __restrict__ W, float* __restrict__ Cp, int M, int N, int K)
{
    constexpr int MF = BM / 32;
    constexpr int NF = 2;
    constexpr int NL = BM / 64;     // ushort8 loads per thread per A matrix
    __shared__ unsigned short sAh[BM * 40], sAl[BM * 40];
    __shared__ unsigned short sBh[64 * 40], sBl[64 * 40];

    const int tid  = threadIdx.x;
    const int w    = tid >> 6;
    const int lane = tid & 63;
    const int wr   = w >> 1;
    const int wc   = w & 1;
    const int lrow = lane & 15;
    const int lkb  = lane >> 4;
    const int row0 = blockIdx.y * BM;
    const int col0 = blockIdx.x * 64;

    const int KS   = K / gridDim.z;
    const int kbeg = blockIdx.z * KS;
    const int kend = kbeg + KS;

    const int srow = tid >> 3;
    const int sfq  = tid & 7;

    f32x4 acc[MF][NF];
    #pragma unroll
    for (int m = 0; m < MF; ++m)
        #pragma unroll
        for (int n = 0; n < NF; ++n)
            acc[m][n] = (f32x4){0.f, 0.f, 0.f, 0.f};

    for (int k0 = kbeg; k0 < kend; k0 += 32) {
        // ---- stage A: BM x 32 bf16, hi+lo, pure copies ----
        #pragma unroll
        for (int j = 0; j < NL; ++j) {
            int idx8 = j * 256 + tid;          // ushort8 units
            int r    = idx8 >> 2;              // row 0..BM-1
            int kq   = (idx8 & 3) * 8;         // 0,8,16,24
            size_t g = (size_t)(row0 + r) * K + k0 + kq;
            *reinterpret_cast<us8*>(sAh + r * 40 + kq) =
                *reinterpret_cast<const us8*>(Ah + g);
            *reinterpret_cast<us8*>(sAl + r * 40 + kq) =
                *reinterpret_cast<const us8*>(Al + g);
        }
        // ---- stage W: 64 x 32 f32, runtime split ----
        #pragma unroll
        for (int p = 0; p < 2; ++p) {
            int r = srow + p * 32;
            float4 v = *reinterpret_cast<const float4*>(
                W + (size_t)(col0 + r) * K + k0 + sfq * 4);
            us4 h, l;
            split4(v, h, l);
            *reinterpret_cast<us4*>(sBh + r * 40 + sfq * 4) = h;
            *reinterpret_cast<us4*>(sBl + r * 40 + sfq * 4) = l;
        }
        __syncthreads();

        short8 ah[MF], al[MF], bh[NF], bl[NF];
        #pragma unroll
        for (int m = 0; m < MF; ++m) {
            int off = (wr * (BM / 2) + m * 16 + lrow) * 40 + lkb * 8;
            ah[m] = *reinterpret_cast<const short8*>(sAh + off);
            al[m] = *reinterpret_cast<const short8*>(sAl + off);
        }
        #pragma unroll
        for (int n = 0; n < NF; ++n) {
            int off = (wc * 32 + n * 16 + lrow) * 40 + lkb * 8;
            bh[n] = *reinterpret_cast<const short8*>(sBh + off);
            bl[n] = *reinterpret_cast<const short8*>(sBl + off);
        }

        #pragma unroll
        for (int m = 0; m < MF; ++m)
            #pragma unroll
            for (int n = 0; n < NF; ++n) {
                acc[m][n] = __builtin_amdgcn_mfma_f32_16x16x32_bf16(
                    ah[m], bh[n], acc[m][n], 0, 0, 0);
                acc[m][n] = __builtin_amdgcn_mfma_f32_16x16x32_bf16(
                    ah[m], bl[n], acc[m][n], 0, 0, 0);
                acc[m][n] = __builtin_amdgcn_mfma_f32_16x16x32_bf16(
                    al[m], bh[n], acc[m][n], 0, 0, 0);
            }
        __syncthreads();
    }

    float* Cb = Cp + (size_t)blockIdx.z * M * N;
    #pragma unroll
    for (int m = 0; m < MF; ++m)
        #pragma unroll
        for (int n = 0; n < NF; ++n) {
            int gr0 = row0 + wr * (BM / 2) + m * 16 + lkb * 4;
            int gc  = col0 + wc * 32 + n * 16 + lrow;
            #pragma unroll
            for (int r = 0; r < 4; ++r)
                Cb[(size_t)(gr0 + r) * N + gc] = acc[m][n][r];
        }
}

// -------- Split-K reduction; EPI=1: softplus(+bias); SPLIT=1: emit bf16 hi/lo ----
// SPLIT writes compact [row][0..2048) hi/lo for cols < 2048 (N may be 2112).
template<int EPI, int SPLIT>
__global__ __launch_bounds__(256) void reduce_splitk(
    const float* __restrict__ part, float* __restrict__ out,
    const float* __restrict__ bias,
    unsigned short* __restrict__ oh, unsigned short* __restrict__ ol,
    int size, int N, int nsplit)
{
    int i = (blockIdx.x * 256 + threadIdx.x) * 4;
    if (i >= size) return;
    float4 s = *reinterpret_cast<const float4*>(part + i);
    for (int p = 1; p < nsplit; ++p) {
        float4 v = *reinterpret_cast<const float4*>(part + (size_t)p * size + i);
        s.x += v.x; s.y += v.y; s.z += v.z; s.w += v.w;
    }
    if (EPI == 1) {
        int col = i % N;
        float4 b = *reinterpret_cast<const float4*>(bias + col);
        s.x = softplus_f(s.x + b.x); s.y = softplus_f(s.y + b.y);
        s.z = softplus_f(s.z + b.z); s.w = softplus_f(s.w + b.w);
    }
    *reinterpret_cast<float4*>(out + i) = s;
    if (SPLIT == 1) {
        int col = i % N;
        if (col < 2048) {
            int row = i / N;
            us4 h, l;
            split4(s, h, l);
            *reinterpret_cast<us4*>(oh + (size_t)row * 2048 + col) = h;
            *reinterpret_cast<us4*>(ol + (size_t)row * 2048 + col) = l;
        }
    }
}

// -------- Depthwise causal conv (k=4) + bias + SiLU, fused bf16 split -----------
__global__ __launch_bounds__(256) void conv_silu_kernel(
    const float* __restrict__ xz, const float* __restrict__ cw,
    const float* __restrict__ cb, float* __restrict__ u,
    unsigned short* __restrict__ uh, unsigned short* __restrict__ ul)
{
    int idx = blockIdx.x * 256 + threadIdx.x;
    int l = idx >> 11;
    int d = idx & (DINNER - 1);
    float acc = cb[d];
    #pragma unroll
    for (int k = 0; k < DCONV; ++k) {
        int ls = l - (DCONV - 1) + k;
        float xv = (ls >= 0) ? xz[(size_t)ls * (2 * DINNER) + d] : 0.f;
        acc = fmaf(xv, cw[d * DCONV + k], acc);
    }
    float v = silu_f(acc);
    u[idx] = v;
    unsigned short h, lo;
    split1(v, h, lo);
    uh[idx] = h; ul[idx] = lo;
}

// -------- Bilinear coefficients: one shared rcp ----------------------------------
__device__ __forceinline__ void bilinear_coef(
    float dt, float a_re, float a_im,
    float& ab_re, float& ab_im, float& co_re, float& co_im)
{
    float dre = fmaf(-dt, a_re, 2.f);
    float dim = -dt * a_im;
    float inv = __builtin_amdgcn_rcpf(fmaf(dre, dre, dim * dim));
    float qre = dre * inv;
    float qim = -dim * inv;
    ab_re = fmaf(4.f, qre, -1.f);
    ab_im = 4.f * qim;
    float t2 = dt + dt;
    co_re = t2 * qre;
    co_im = t2 * qim;
}

// -------- Chunked scan, pass 1: per-chunk (P, S), 2 d-chains per thread ----------
// grid = (DINNER/8) * NCHUNK = 4096 blocks x 64 threads.
__global__ __launch_bounds__(64) void scan_chunk_kernel(
    const float* __restrict__ delta, const float* __restrict__ ssm,
    const float* __restrict__ u,
    const float* __restrict__ A_log_re, const float* __restrict__ A_log_im,
    float2* __restrict__ Pc, float2* __restrict__ Sc)
{
    const int b = blockIdx.x;
    const int chunk = b >> 8;
    const int dg = b & 255;
    const int tid = threadIdx.x;
    const int n = tid & 15;
    const int dloc = tid >> 4;
    const int d0 = dg * 8 + dloc;
    const int d1 = d0 + 4;

    float m0 = expf(A_log_re[d0 * DSTATE + n]);
    float i0 = A_log_im[d0 * DSTATE + n];
    float a0r = -m0 * cosf(i0), a0i = -m0 * sinf(i0);
    float m1 = expf(A_log_re[d1 * DSTATE + n]);
    float i1 = A_log_im[d1 * DSTATE + n];
    float a1r = -m1 * cosf(i1), a1i = -m1 * sinf(i1);

    float p0r = 1.f, p0i = 0.f, s0r = 0.f, s0i = 0.f;
    float p1r = 1.f, p1i = 0.f, s1r = 0.f, s1i = 0.f;

    const int l0 = chunk * CHUNK;
    #pragma unroll 2
    for (int i = 0; i < CHUNK; ++i) {
        const int l = l0 + i;
        float dt0 = delta[(size_t)l * DINNER + d0];
        float dt1 = delta[(size_t)l * DINNER + d1];
        float uv0 = u[(size_t)l * DINNER + d0];
        float uv1 = u[(size_t)l * DINNER + d1];
        const float* srow = ssm + (size_t)l * NPROJ + DINNER;
        float br = srow[n];
        float bi = srow[DSTATE + n];

        float abr, abi, cor, coi;
        bilinear_coef(dt0, a0r, a0i, abr, abi, cor, coi);
        {
            float cbr = cor * br - coi * bi;
            float cbi = cor * bi + coi * br;
            float ur = cbr * uv0, ui = cbi * uv0;
            float sr = abr * s0r - abi * s0i + ur;
            float si = abr * s0i + abi * s0r + ui;
            s0r = sr; s0i = si;
            float pr = abr * p0r - abi * p0i;
            float pi = abr * p0i + abi * p0r;
            p0r = pr; p0i = pi;
        }
        bilinear_coef(dt1, a1r, a1i, abr, abi, cor, coi);
        {
            float cbr = cor * br - coi * bi;
            float cbi = cor * bi + coi * br;
            float ur = cbr * uv1, ui = cbi * uv1;
            float sr = abr * s1r - abi * s1i + ur;
            float si = abr * s1i + abi * s1r + ui;
            s1r = sr; s1i = si;
            float pr = abr * p1r - abi * p1i;
            float pi = abr * p1i + abi * p1r;
            p1r = pr; p1i = pi;
        }
    }

    int idx0 = chunk * NDN + d0 * DSTATE + n;
    int idx1 = chunk * NDN + d1 * DSTATE + n;
    Pc[idx0] = make_float2(p0r, p0i);
    Sc[idx0] = make_float2(s0r, s0i);
    Pc[idx1] = make_float2(p1r, p1i);
    Sc[idx1] = make_float2(s1r, s1i);
}

// -------- Chunked scan, pass 2: sequential combine -------------------------------
__global__ __launch_bounds__(256) void scan_combine_kernel(
    float2* __restrict__ Pc, const float2* __restrict__ Sc)
{
    const int td = blockIdx.x * 256 + threadIdx.x;
    float h_re = 0.f, h_im = 0.f;
    #pragma unroll
    for (int c = 0; c < NCHUNK; ++c) {
        float2 p = Pc[c * NDN + td];
        float2 s = Sc[c * NDN + td];
        Pc[c * NDN + td] = make_float2(h_re, h_im);
        float nr = s.x + p.x * h_re - p.y * h_im;
        float ni = s.y + p.x * h_im + p.y * h_re;
        h_re = nr; h_im = ni;
    }
}

// -------- Chunked scan, pass 3: re-scan, emit y as bf16 hi/lo --------------------
__global__ __launch_bounds__(64) void scan_final_kernel(
    const float* __restrict__ delta, const float* __restrict__ ssm,
    const float* __restrict__ u, const float* __restrict__ xz,
    const float* __restrict__ A_log_re, const float* __restrict__ A_log_im,
    const float* __restrict__ Dvec, const float2* __restrict__ Hin,
    unsigned short* __restrict__ yh, unsigned short* __restrict__ yl)
{
    const int b = blockIdx.x;
    const int chunk = b >> 8;
    const int dg = b & 255;
    const int tid = threadIdx.x;
    const int n = tid & 15;
    const int dloc = tid >> 4;
    const int d0 = dg * 8 + dloc;
    const int d1 = d0 + 4;

    float m0 = expf(A_log_re[d0 * DSTATE + n]);
    float i0 = A_log_im[d0 * DSTATE + n];
    float a0r = -m0 * cosf(i0), a0i = -m0 * sinf(i0);
    float m1 = expf(A_log_re[d1 * DSTATE + n]);
    float i1 = A_log_im[d1 * DSTATE + n];
    float a1r = -m1 * cosf(i1), a1i = -m1 * sinf(i1);
    float Dd0 = Dvec[d0], Dd1 = Dvec[d1];

    float2 h0 = Hin[chunk * NDN + d0 * DSTATE + n];
    float2 h1 = Hin[chunk * NDN + d1 * DSTATE + n];
    float h0r = h0.x, h0i = h0.y, h1r = h1.x, h1i = h1.y;

    const int l0 = chunk * CHUNK;
    #pragma unroll 2
    for (int i = 0; i < CHUNK; ++i) {
        const int l = l0 + i;
        float dt0 = delta[(size_t)l * DINNER + d0];
        float dt1 = delta[(size_t)l * DINNER + d1];
        float uv0 = u[(size_t)l * DINNER + d0];
        float uv1 = u[(size_t)l * DINNER + d1];
        const float* srow = ssm + (size_t)l * NPROJ + DINNER;
        float br = srow[n];
        float bi = srow[DSTATE + n];
        float cr = srow[2 * DSTATE + n];
        float ci = srow[3 * DSTATE + n];

        float abr, abi, cor, coi;
        bilinear_coef(dt0, a0r, a0i, abr, abi, cor, coi);
        float c0;
        {
            float cbr = cor * br - coi * bi;
            float cbi = cor * bi + coi * br;
            float hr = abr * h0r - abi * h0i + cbr * uv0;
            float hi = abr * h0i + abi * h0r + cbi * uv0;
            h0r = hr; h0i = hi;
            c0 = cr * h0r - ci * h0i;
        }
        bilinear_coef(dt1, a1r, a1i, abr, abi, cor, coi);
        float c1;
        {
            float cbr = cor * br - coi * bi;
            float cbi = cor * bi + coi * br;
            float hr = abr * h1r - abi * h1i + cbr * uv1;
            float hi = abr * h1i + abi * h1r + cbi * uv1;
            h1r = hr; h1i = hi;
            c1 = cr * h1r - ci * h1i;
        }
        c0 += __shfl_xor(c0, 1, 16);
        c0 += __shfl_xor(c0, 2, 16);
        c0 += __shfl_xor(c0, 4, 16);
        c0 += __shfl_xor(c0, 8, 16);
        c1 += __shfl_xor(c1, 1, 16);
        c1 += __shfl_xor(c1, 2, 16);
        c1 += __shfl_xor(c1, 4, 16);
        c1 += __shfl_xor(c1, 8, 16);
        if (n == 0) {
            float zv0 = xz[(size_t)l * (2 * DINNER) + DINNER + d0];
            float zv1 = xz[(size_t)l * (2 * DINNER) + DINNER + d1];
            float o0 = (c0 + Dd0 * uv0) * silu_f(zv0);
            float o1 = (c1 + Dd1 * uv1) * silu_f(zv1);
            unsigned short hh, ll;
            split1(o0, hh, ll);
            yh[(size_t)l * DINNER + d0] = hh; yl[(size_t)l * DINNER + d0] = ll;
            split1(o1, hh, ll);
            yh[(size_t)l * DINNER + d1] = hh; yl[(size_t)l * DINNER + d1] = ll;
        }
    }
}

extern "C" void kernel_launch(void* const* d_in, const int* in_sizes, int n_in,
                              void* d_out, int out_size, void* d_ws, size_t ws_size,
                              hipStream_t stream)
{
    const float* x         = (const float*)d_in[0];
    const float* in_proj_w = (const float*)d_in[1];
    const float* conv_w    = (const float*)d_in[2];
    const float* conv_b    = (const float*)d_in[3];
    const float* x_proj_w  = (const float*)d_in[4];
    const float* dt_proj_w = (const float*)d_in[5];
    const float* dt_proj_b = (const float*)d_in[6];
    const float* A_log_re  = (const float*)d_in[7];
    const float* A_log_im  = (const float*)d_in[8];
    const float* Dvec      = (const float*)d_in[9];
    const float* out_proj_w= (const float*)d_in[10];
    float* out = (float*)d_out;

    float* ws    = (float*)d_ws;
    float* xz    = ws;                                      // 4,194,304 f
    float* u     = xz    + (size_t)L_SEQ * 2 * DINNER;      // 2,097,152 f
    float* ssm   = u     + (size_t)L_SEQ * DINNER;          // 2,162,688 f
    float* delta = ssm   + (size_t)L_SEQ * NPROJ;           // 2,097,152 f
    float2* Pc   = (float2*)(delta + (size_t)L_SEQ * DINNER); // 1,048,576 f
    float2* Sc   = Pc + (size_t)NCHUNK * NDN;               // 1,048,576 f
    float* part  = (float*)(Sc + (size_t)NCHUNK * NDN);     // 8,650,752 f
    unsigned short* uh = (unsigned short*)(part + (size_t)4 * L_SEQ * NPROJ);
    unsigned short* ul = uh + (size_t)L_SEQ * DINNER;       // each 2,097,152 us
    unsigned short* sh = ul + (size_t)L_SEQ * DINNER;
    unsigned short* sl = sh + (size_t)L_SEQ * DINNER;
    unsigned short* yh = sl + (size_t)L_SEQ * DINNER;
    unsigned short* yl = yh + (size_t)L_SEQ * DINNER;

    // 1) xz = x @ in_proj_w.T   (1024 x 4096, K=1024, SK=2)
    gemm_mfma_sk<128><<<dim3((2 * DINNER) / 64, L_SEQ / 128, 2), 256, 0, stream>>>(
        x, in_proj_w, part, L_SEQ, 2 * DINNER, DMODEL, DMODEL);
    reduce_splitk<0, 0><<<(L_SEQ * 2 * DINNER) / 1024, 256, 0, stream>>>(
        part, xz, nullptr, nullptr, nullptr, L_SEQ * 2 * DINNER, 2 * DINNER, 2);

    // 2) conv + SiLU -> u (f32) + uh/ul (bf16 split)
    conv_silu_kernel<<<(L_SEQ * DINNER) / 256, 256, 0, stream>>>(
        xz, conv_w, conv_b, u, uh, ul);

    // 3) ssm = u @ x_proj_w.T   (1024 x 2112, K=2048, SK=4), pre-split A
    gemm_bf16a_sk<128><<<dim3(NPROJ / 64, L_SEQ / 128, 4), 256, 0, stream>>>(
        uh, ul, x_proj_w, part, L_SEQ, NPROJ, DINNER);
    reduce_splitk<0, 1><<<(L_SEQ * NPROJ) / 1024, 256, 0, stream>>>(
        part, ssm, nullptr, sh, sl, L_SEQ * NPROJ, NPROJ, 4);

    // 4) delta = softplus(ssm[:, :2048] @ dt_proj_w.T + dt_proj_b)  (SK=4)
    gemm_bf16a_sk<128><<<dim3(DINNER / 64, L_SEQ / 128, 4), 256, 0, stream>>>(
        sh, sl, dt_proj_w, part, L_SEQ, DINNER, DINNER);
    reduce_splitk<1, 0><<<(L_SEQ * DINNER) / 1024, 256, 0, stream>>>(
        part, delta, dt_proj_b, nullptr, nullptr, L_SEQ * DINNER, DINNER, 4);

    // 5) chunk-parallel complex scan -> yh/yl (bf16 split, f32 y dropped)
    scan_chunk_kernel<<<(DINNER / 8) * NCHUNK, 64, 0, stream>>>(
        delta, ssm, u, A_log_re, A_log_im, Pc, Sc);
    scan_combine_kernel<<<NDN / 256, 256, 0, stream>>>(Pc, Sc);
    scan_final_kernel<<<(DINNER / 8) * NCHUNK, 64, 0, stream>>>(
        delta, ssm, u, xz, A_log_re, A_log_im, Dvec, Pc, yh, yl);

    // 6) out = y @ out_proj_w.T  (1024 x 1024, K=2048, BM=64, SK=4)
    gemm_bf16a_sk<64><<<dim3(DMODEL / 64, L_SEQ / 64, 4), 256, 0, stream>>>(
        yh, yl, out_proj_w, part, L_SEQ, DMODEL, DINNER);
    reduce_splitk<0, 0><<<(L_SEQ * DMODEL) / 1024, 256, 0, stream>>>(
        part, out, nullptr, nullptr, nullptr, L_SEQ * DMODEL, DMODEL, 4);
}

// Round 16
// 429.216 us; speedup vs baseline: 1.0219x; 1.0219x over previous
//
#include <hip/hip_runtime.h>
#include <hip/hip_bf16.h>
#include <math.h>

// Problem constants
#define L_SEQ   1024
#define DMODEL  1024
#define DINNER  2048
#define DSTATE  16
#define DCONV   4
#define NPROJ   (DINNER + 4 * DSTATE)   // 2112
#define NCHUNK  16
#define CHUNK   64                       // L_SEQ / NCHUNK
#define NDN     (DINNER * DSTATE)        // 32768 (d,n) pairs

typedef __attribute__((ext_vector_type(8))) short  short8;
typedef __attribute__((ext_vector_type(8))) unsigned short us8;
typedef __attribute__((ext_vector_type(4))) float  f32x4;
typedef __attribute__((ext_vector_type(4))) unsigned short us4;

__device__ __forceinline__ float softplus_f(float v) {
    return fmaxf(v, 0.f) + log1pf(expf(-fabsf(v)));
}
__device__ __forceinline__ float silu_f(float v) {
    return v * __builtin_amdgcn_rcpf(1.f + expf(-v));
}

// Split f32 into bf16 hi (truncated) + bf16 lo (rounded residual).
__device__ __forceinline__ void split1(float x, unsigned short& h, unsigned short& l) {
    unsigned b  = __float_as_uint(x);
    unsigned hb = b & 0xffff0000u;
    float    r  = x - __uint_as_float(hb);
    unsigned rb = __float_as_uint(r) + 0x8000u;
    h = (unsigned short)(hb >> 16);
    l = (unsigned short)(rb >> 16);
}
__device__ __forceinline__ void split4(float4 v, us4& h, us4& l) {
    float vv[4] = {v.x, v.y, v.z, v.w};
    #pragma unroll
    for (int i = 0; i < 4; ++i) {
        unsigned b  = __float_as_uint(vv[i]);
        unsigned hb = b & 0xffff0000u;
        float    r  = vv[i] - __uint_as_float(hb);
        unsigned rb = __float_as_uint(r) + 0x8000u;
        h[i] = (unsigned short)(hb >> 16);
        l[i] = (unsigned short)(rb >> 16);
    }
}

// -------- Elementwise f32 -> bf16 hi/lo pre-split (prep pass) --------------------
__global__ __launch_bounds__(256) void split_kernel(
    const float* __restrict__ in, unsigned short* __restrict__ h,
    unsigned short* __restrict__ l)
{
    int i = (blockIdx.x * 256 + threadIdx.x) * 4;
    float4 v = *reinterpret_cast<const float4*>(in + i);
    us4 hh, ll;
    split4(v, hh, ll);
    *reinterpret_cast<us4*>(h + i) = hh;
    *reinterpret_cast<us4*>(l + i) = ll;
}

// -------- MFMA GEMM, BOTH sides pre-split bf16 (pure-copy staging) ---------------
// Cp[kz][M][N] partials. BM in {128,64}, BN=64, BK=32. 256 thr = 4 waves (2x2).
template<int BM>
__global__ __launch_bounds__(256) void gemm_bf16ab_sk(
    const unsigned short* __restrict__ Ah, const unsigned short* __restrict__ Al,
    const unsigned short* __restrict__ Wh, const unsigned short* __restrict__ Wl,
    float* __restrict__ Cp, int M, int N, int K)
{
    constexpr int MF  = BM / 32;
    constexpr int NF  = 2;
    constexpr int NLA = BM / 64;    // us8 loads per thread per A plane
    __shared__ unsigned short sAh[BM * 40], sAl[BM * 40];
    __shared__ unsigned short sBh[64 * 40], sBl[64 * 40];

    const int tid  = threadIdx.x;
    const int w    = tid >> 6;
    const int lane = tid & 63;
    const int wr   = w >> 1;
    const int wc   = w & 1;
    const int lrow = lane & 15;
    const int lkb  = lane >> 4;
    const int row0 = blockIdx.y * BM;
    const int col0 = blockIdx.x * 64;

    const int KS   = K / gridDim.z;
    const int kbeg = blockIdx.z * KS;
    const int kend = kbeg + KS;

    f32x4 acc[MF][NF];
    #pragma unroll
    for (int m = 0; m < MF; ++m)
        #pragma unroll
        for (int n = 0; n < NF; ++n)
            acc[m][n] = (f32x4){0.f, 0.f, 0.f, 0.f};

    const int wrow = tid >> 2;           // 0..63 (W row)
    const int wkq  = (tid & 3) * 8;      // 0,8,16,24

    for (int k0 = kbeg; k0 < kend; k0 += 32) {
        // ---- stage A: BM x 32, hi+lo, pure us8 copies ----
        #pragma unroll
        for (int j = 0; j < NLA; ++j) {
            int idx8 = j * 256 + tid;
            int r    = idx8 >> 2;
            int kq   = (idx8 & 3) * 8;
            size_t g = (size_t)(row0 + r) * K + k0 + kq;
            *reinterpret_cast<us8*>(sAh + r * 40 + kq) =
                *reinterpret_cast<const us8*>(Ah + g);
            *reinterpret_cast<us8*>(sAl + r * 40 + kq) =
                *reinterpret_cast<const us8*>(Al + g);
        }
        // ---- stage W: 64 x 32, hi+lo, pure us8 copies ----
        {
            size_t g = (size_t)(col0 + wrow) * K + k0 + wkq;
            *reinterpret_cast<us8*>(sBh + wrow * 40 + wkq) =
                *reinterpret_cast<const us8*>(Wh + g);
            *reinterpret_cast<us8*>(sBl + wrow * 40 + wkq) =
                *reinterpret_cast<const us8*>(Wl + g);
        }
        __syncthreads();

        short8 ah[MF], al[MF], bh[NF], bl[NF];
        #pragma unroll
        for (int m = 0; m < MF; ++m) {
            int off = (wr * (BM / 2) + m * 16 + lrow) * 40 + lkb * 8;
            ah[m] = *reinterpret_cast<const short8*>(sAh + off);
            al[m] = *reinterpret_cast<const short8*>(sAl + off);
        }
        #pragma unroll
        for (int n = 0; n < NF; ++n) {
            int off = (wc * 32 + n * 16 + lrow) * 40 + lkb * 8;
            bh[n] = *reinterpret_cast<const short8*>(sBh + off);
            bl[n] = *reinterpret_cast<const short8*>(sBl + off);
        }

        #pragma unroll
        for (int m = 0; m < MF; ++m)
            #pragma unroll
            for (int n = 0; n < NF; ++n) {
                acc[m][n] = __builtin_amdgcn_mfma_f32_16x16x32_bf16(
                    ah[m], bh[n], acc[m][n], 0, 0, 0);
                acc[m][n] = __builtin_amdgcn_mfma_f32_16x16x32_bf16(
                    ah[m], bl[n], acc[m][n], 0, 0, 0);
                acc[m][n] = __builtin_amdgcn_mfma_f32_16x16x32_bf16(
                    al[m], bh[n], acc[m][n], 0, 0, 0);
            }
        __syncthreads();
    }

    float* Cb = Cp + (size_t)blockIdx.z * M * N;
    #pragma unroll
    for (int m = 0; m < MF; ++m)
        #pragma unroll
        for (int n = 0; n < NF; ++n) {
            int gr0 = row0 + wr * (BM / 2) + m * 16 + lkb * 4;
            int gc  = col0 + wc * 32 + n * 16 + lrow;
            #pragma unroll
            for (int r = 0; r < 4; ++r)
                Cb[(size_t)(gr0 + r) * N + gc] = acc[m][n][r];
        }
}

// -------- Fallback GEMMs (runtime split) — used only if ws too small -------------
template<int BM>
__global__ __launch_bounds__(256) void gemm_mfma_sk(
    const float* __restrict__ A, const float* __restrict__ W,
    float* __restrict__ Cp, int M, int N, int K, int lda)
{
    constexpr int MF = BM / 32;
    constexpr int NF = 2;
    __shared__ unsigned short sAh[BM * 40], sAl[BM * 40];
    __shared__ unsigned short sBh[64 * 40], sBl[64 * 40];
    const int tid  = threadIdx.x;
    const int w    = tid >> 6;
    const int lane = tid & 63;
    const int wr   = w >> 1;
    const int wc   = w & 1;
    const int lrow = lane & 15;
    const int lkb  = lane >> 4;
    const int row0 = blockIdx.y * BM;
    const int col0 = blockIdx.x * 64;
    const int KS   = K / gridDim.z;
    const int kbeg = blockIdx.z * KS;
    const int kend = kbeg + KS;
    const int srow = tid >> 3;
    const int sfq  = tid & 7;

    f32x4 acc[MF][NF];
    #pragma unroll
    for (int m = 0; m < MF; ++m)
        #pragma unroll
        for (int n = 0; n < NF; ++n)
            acc[m][n] = (f32x4){0.f, 0.f, 0.f, 0.f};

    for (int k0 = kbeg; k0 < kend; k0 += 32) {
        #pragma unroll
        for (int p = 0; p < BM / 32; ++p) {
            int r = srow + p * 32;
            float4 v = *reinterpret_cast<const float4*>(
                A + (size_t)(row0 + r) * lda + k0 + sfq * 4);
            us4 h, l;
            split4(v, h, l);
            *reinterpret_cast<us4*>(sAh + r * 40 + sfq * 4) = h;
            *reinterpret_cast<us4*>(sAl + r * 40 + sfq * 4) = l;
        }
        #pragma unroll
        for (int p = 0; p < 2; ++p) {
            int r = srow + p * 32;
            float4 v = *reinterpret_cast<const float4*>(
                W + (size_t)(col0 + r) * K + k0 + sfq * 4);
            us4 h, l;
            split4(v, h, l);
            *reinterpret_cast<us4*>(sBh + r * 40 + sfq * 4) = h;
            *reinterpret_cast<us4*>(sBl + r * 40 + sfq * 4) = l;
        }
        __syncthreads();
        short8 ah[MF], al[MF], bh[NF], bl[NF];
        #pragma unroll
        for (int m = 0; m < MF; ++m) {
            int off = (wr * (BM / 2) + m * 16 + lrow) * 40 + lkb * 8;
            ah[m] = *reinterpret_cast<const short8*>(sAh + off);
            al[m] = *reinterpret_cast<const short8*>(sAl + off);
        }
        #pragma unroll
        for (int n = 0; n < NF; ++n) {
            int off = (wc * 32 + n * 16 + lrow) * 40 + lkb * 8;
            bh[n] = *reinterpret_cast<const short8*>(sBh + off);
            bl[n] = *reinterpret_cast<const short8*>(sBl + off);
        }
        #pragma unroll
        for (int m = 0; m < MF; ++m)
            #pragma unroll
            for (int n = 0; n < NF; ++n) {
                acc[m][n] = __builtin_amdgcn_mfma_f32_16x16x32_bf16(
                    ah[m], bh[n], acc[m][n], 0, 0, 0);
                acc[m][n] = __builtin_amdgcn_mfma_f32_16x16x32_bf16(
                    ah[m], bl[n], acc[m][n], 0, 0, 0);
                acc[m][n] = __builtin_amdgcn_mfma_f32_16x16x32_bf16(
                    al[m], bh[n], acc[m][n], 0, 0, 0);
            }
        __syncthreads();
    }
    float* Cb = Cp + (size_t)blockIdx.z * M * N;
    #pragma unroll
    for (int m = 0; m < MF; ++m)
        #pragma unroll
        for (int n = 0; n < NF; ++n) {
            int gr0 = row0 + wr * (BM / 2) + m * 16 + lkb * 4;
            int gc  = col0 + wc * 32 + n * 16 + lrow;
            #pragma unroll
            for (int r = 0; r < 4; ++r)
                Cb[(size_t)(gr0 + r) * N + gc] = acc[m][n][r];
        }
}

template<int BM>
__global__ __launch_bounds__(256) void gemm_bf16a_sk(
    const unsigned short* __restrict__ Ah, const unsigned short* __restrict__ Al,
    const float* __restrict__ W, float* __restrict__ Cp, int M, int N, int K)
{
    constexpr int MF = BM / 32;
    constexpr int NF = 2;
    constexpr int NL = BM / 64;
    __shared__ unsigned short sAh[BM * 40], sAl[BM * 40];
    __shared__ unsigned short sBh[64 * 40], sBl[64 * 40];
    const int tid  = threadIdx.x;
    const int w    = tid >> 6;
    const int lane = tid & 63;
    const int wr   = w >> 1;
    const int wc   = w & 1;
    const int lrow = lane & 15;
    const int lkb  = lane >> 4;
    const int row0 = blockIdx.y * BM;
    const int col0 = blockIdx.x * 64;
    const int KS   = K / gridDim.z;
    const int kbeg = blockIdx.z * KS;
    const int kend = kbeg + KS;
    const int srow = tid >> 3;
    const int sfq  = tid & 7;

    f32x4 acc[MF][NF];
    #pragma unroll
    for (int m = 0; m < MF; ++m)
        #pragma unroll
        for (int n = 0; n < NF; ++n)
            acc[m][n] = (f32x4){0.f, 0.f, 0.f, 0.f};

    for (int k0 = kbeg; k0 < kend; k0 += 32) {
        #pragma unroll
        for (int j = 0; j < NL; ++j) {
            int idx8 = j * 256 + tid;
            int r    = idx8 >> 2;
            int kq   = (idx8 & 3) * 8;
            size_t g = (size_t)(row0 + r) * K + k0 + kq;
            *reinterpret_cast<us8*>(sAh + r * 40 + kq) =
                *reinterpret_cast<const us8*>(Ah + g);
            *reinterpret_cast<us8*>(sAl + r * 40 + kq) =
                *reinterpret_cast<const us8*>(Al + g);
        }
        #pragma unroll
        for (int p = 0; p < 2; ++p) {
            int r = srow + p * 32;
            float4 v = *reinterpret_cast<const float4*>(
                W + (size_t)(col0 + r) * K + k0 + sfq * 4);
            us4 h, l;
            split4(v, h, l);
            *reinterpret_cast<us4*>(sBh + r * 40 + sfq * 4) = h;
            *reinterpret_cast<us4*>(sBl + r * 40 + sfq * 4) = l;
        }
        __syncthreads();
        short8 ah[MF], al[MF], bh[NF], bl[NF];
        #pragma unroll
        for (int m = 0; m < MF; ++m) {
            int off = (wr * (BM / 2) + m * 16 + lrow) * 40 + lkb * 8;
            ah[m] = *reinterpret_cast<const short8*>(sAh + off);
            al[m] = *reinterpret_cast<const short8*>(sAl + off);
        }
        #pragma unroll
        for (int n = 0; n < NF; ++n) {
            int off = (wc * 32 + n * 16 + lrow) * 40 + lkb * 8;
            bh[n] = *reinterpret_cast<const short8*>(sBh + off);
            bl[n] = *reinterpret_cast<const short8*>(sBl + off);
        }
        #pragma unroll
        for (int m = 0; m < MF; ++m)
            #pragma unroll
            for (int n = 0; n < NF; ++n) {
                acc[m][n] = __builtin_amdgcn_mfma_f32_16x16x32_bf16(
                    ah[m], bh[n], acc[m][n], 0, 0, 0);
                acc[m][n] = __builtin_amdgcn_mfma_f32_16x16x32_bf16(
                    ah[m], bl[n], acc[m][n], 0, 0, 0);
                acc[m][n] = __builtin_amdgcn_mfma_f32_16x16x32_bf16(
                    al[m], bh[n], acc[m][n], 0, 0, 0);
            }
        __syncthreads();
    }
    float* Cb = Cp + (size_t)blockIdx.z * M * N;
    #pragma unroll
    for (int m = 0; m < MF; ++m)
        #pragma unroll
        for (int n = 0; n < NF; ++n) {
            int gr0 = row0 + wr * (BM / 2) + m * 16 + lkb * 4;
            int gc  = col0 + wc * 32 + n * 16 + lrow;
            #pragma unroll
            for (int r = 0; r < 4; ++r)
                Cb[(size_t)(gr0 + r) * N + gc] = acc[m][n][r];
        }
}

// -------- Split-K reduction; EPI=1: softplus(+bias); SPLIT=1: emit bf16 hi/lo ----
template<int EPI, int SPLIT>
__global__ __launch_bounds__(256) void reduce_splitk(
    const float* __restrict__ part, float* __restrict__ out,
    const float* __restrict__ bias,
    unsigned short* __restrict__ oh, unsigned short* __restrict__ ol,
    int size, int N, int nsplit)
{
    int i = (blockIdx.x * 256 + threadIdx.x) * 4;
    if (i >= size) return;
    float4 s = *reinterpret_cast<const float4*>(part + i);
    for (int p = 1; p < nsplit; ++p) {
        float4 v = *reinterpret_cast<const float4*>(part + (size_t)p * size + i);
        s.x += v.x; s.y += v.y; s.z += v.z; s.w += v.w;
    }
    if (EPI == 1) {
        int col = i % N;
        float4 b = *reinterpret_cast<const float4*>(bias + col);
        s.x = softplus_f(s.x + b.x); s.y = softplus_f(s.y + b.y);
        s.z = softplus_f(s.z + b.z); s.w = softplus_f(s.w + b.w);
    }
    *reinterpret_cast<float4*>(out + i) = s;
    if (SPLIT == 1) {
        int col = i % N;
        if (col < 2048) {
            int row = i / N;
            us4 h, l;
            split4(s, h, l);
            *reinterpret_cast<us4*>(oh + (size_t)row * 2048 + col) = h;
            *reinterpret_cast<us4*>(ol + (size_t)row * 2048 + col) = l;
        }
    }
}

// -------- Depthwise causal conv (k=4) + bias + SiLU, fused bf16 split -----------
__global__ __launch_bounds__(256) void conv_silu_kernel(
    const float* __restrict__ xz, const float* __restrict__ cw,
    const float* __restrict__ cb, float* __restrict__ u,
    unsigned short* __restrict__ uh, unsigned short* __restrict__ ul)
{
    int idx = blockIdx.x * 256 + threadIdx.x;
    int l = idx >> 11;
    int d = idx & (DINNER - 1);
    float acc = cb[d];
    #pragma unroll
    for (int k = 0; k < DCONV; ++k) {
        int ls = l - (DCONV - 1) + k;
        float xv = (ls >= 0) ? xz[(size_t)ls * (2 * DINNER) + d] : 0.f;
        acc = fmaf(xv, cw[d * DCONV + k], acc);
    }
    float v = silu_f(acc);
    u[idx] = v;
    unsigned short h, lo;
    split1(v, h, lo);
    uh[idx] = h; ul[idx] = lo;
}

// -------- Bilinear coefficients: one shared rcp ----------------------------------
__device__ __forceinline__ void bilinear_coef(
    float dt, float a_re, float a_im,
    float& ab_re, float& ab_im, float& co_re, float& co_im)
{
    float dre = fmaf(-dt, a_re, 2.f);
    float dim = -dt * a_im;
    float inv = __builtin_amdgcn_rcpf(fmaf(dre, dre, dim * dim));
    float qre = dre * inv;
    float qim = -dim * inv;
    ab_re = fmaf(4.f, qre, -1.f);
    ab_im = 4.f * qim;
    float t2 = dt + dt;
    co_re = t2 * qre;
    co_im = t2 * qim;
}

// -------- Chunked scan, pass 1 (ILP-1, 8192 blocks) ------------------------------
__global__ __launch_bounds__(64) void scan_chunk_kernel(
    const float* __restrict__ delta, const float* __restrict__ ssm,
    const float* __restrict__ u,
    const float* __restrict__ A_log_re, const float* __restrict__ A_log_im,
    float2* __restrict__ Pc, float2* __restrict__ Sc)
{
    const int b = blockIdx.x;
    const int chunk = b >> 9;
    const int d4 = b & 511;
    const int tid = threadIdx.x;
    const int n = tid & 15;
    const int dloc = tid >> 4;
    const int d = d4 * 4 + dloc;

    const float mag  = expf(A_log_re[d * DSTATE + n]);
    const float alim = A_log_im[d * DSTATE + n];
    const float a_re = -mag * cosf(alim);
    const float a_im = -mag * sinf(alim);

    float p_re = 1.f, p_im = 0.f;
    float s_re = 0.f, s_im = 0.f;

    const int l0 = chunk * CHUNK;
    #pragma unroll 4
    for (int i = 0; i < CHUNK; ++i) {
        const int l = l0 + i;
        float dt = delta[(size_t)l * DINNER + d];
        float uv = u[(size_t)l * DINNER + d];
        const float* srow = ssm + (size_t)l * NPROJ + DINNER;
        float br = srow[n];
        float bi = srow[DSTATE + n];

        float ab_re, ab_im, co_re, co_im;
        bilinear_coef(dt, a_re, a_im, ab_re, ab_im, co_re, co_im);
        float cbr = co_re * br - co_im * bi;
        float cbi = co_re * bi + co_im * br;
        float ub_re = cbr * uv;
        float ub_im = cbi * uv;

        float sr = ab_re * s_re - ab_im * s_im + ub_re;
        float si = ab_re * s_im + ab_im * s_re + ub_im;
        s_re = sr; s_im = si;
        float pr = ab_re * p_re - ab_im * p_im;
        float pi = ab_re * p_im + ab_im * p_re;
        p_re = pr; p_im = pi;
    }

    const int idx = chunk * NDN + d * DSTATE + n;
    Pc[idx] = make_float2(p_re, p_im);
    Sc[idx] = make_float2(s_re, s_im);
}

// -------- Chunked scan, pass 2: sequential combine -------------------------------
__global__ __launch_bounds__(256) void scan_combine_kernel(
    float2* __restrict__ Pc, const float2* __restrict__ Sc)
{
    const int td = blockIdx.x * 256 + threadIdx.x;
    float h_re = 0.f, h_im = 0.f;
    #pragma unroll
    for (int c = 0; c < NCHUNK; ++c) {
        float2 p = Pc[c * NDN + td];
        float2 s = Sc[c * NDN + td];
        Pc[c * NDN + td] = make_float2(h_re, h_im);
        float nr = s.x + p.x * h_re - p.y * h_im;
        float ni = s.y + p.x * h_im + p.y * h_re;
        h_re = nr; h_im = ni;
    }
}

// -------- Chunked scan, pass 3 (ILP-1): re-scan, emit y as bf16 hi/lo ------------
__global__ __launch_bounds__(64) void scan_final_kernel(
    const float* __restrict__ delta, const float* __restrict__ ssm,
    const float* __restrict__ u, const float* __restrict__ xz,
    const float* __restrict__ A_log_re, const float* __restrict__ A_log_im,
    const float* __restrict__ Dvec, const float2* __restrict__ Hin,
    unsigned short* __restrict__ yh, unsigned short* __restrict__ yl)
{
    const int b = blockIdx.x;
    const int chunk = b >> 9;
    const int d4 = b & 511;
    const int tid = threadIdx.x;
    const int n = tid & 15;
    const int dloc = tid >> 4;
    const int d = d4 * 4 + dloc;

    const float mag  = expf(A_log_re[d * DSTATE + n]);
    const float alim = A_log_im[d * DSTATE + n];
    const float a_re = -mag * cosf(alim);
    const float a_im = -mag * sinf(alim);
    const float Dd   = Dvec[d];

    float2 h0 = Hin[chunk * NDN + d * DSTATE + n];
    float h_re = h0.x, h_im = h0.y;

    const int l0 = chunk * CHUNK;
    #pragma unroll 2
    for (int i = 0; i < CHUNK; ++i) {
        const int l = l0 + i;
        float dt = delta[(size_t)l * DINNER + d];
        float uv = u[(size_t)l * DINNER + d];
        const float* srow = ssm + (size_t)l * NPROJ + DINNER;
        float br = srow[n];
        float bi = srow[DSTATE + n];
        float cr = srow[2 * DSTATE + n];
        float ci = srow[3 * DSTATE + n];

        float ab_re, ab_im, co_re, co_im;
        bilinear_coef(dt, a_re, a_im, ab_re, ab_im, co_re, co_im);
        float cbr = co_re * br - co_im * bi;
        float cbi = co_re * bi + co_im * br;

        float hr = ab_re * h_re - ab_im * h_im + cbr * uv;
        float hi = ab_re * h_im + ab_im * h_re + cbi * uv;
        h_re = hr; h_im = hi;

        float contrib = cr * h_re - ci * h_im;
        contrib += __shfl_xor(contrib, 1, 16);
        contrib += __shfl_xor(contrib, 2, 16);
        contrib += __shfl_xor(contrib, 4, 16);
        contrib += __shfl_xor(contrib, 8, 16);
        if (n == 0) {
            float zv = xz[(size_t)l * (2 * DINNER) + DINNER + d];
            float o = (contrib + Dd * uv) * silu_f(zv);
            unsigned short hh, ll;
            split1(o, hh, ll);
            yh[(size_t)l * DINNER + d] = hh;
            yl[(size_t)l * DINNER + d] = ll;
        }
    }
}

extern "C" void kernel_launch(void* const* d_in, const int* in_sizes, int n_in,
                              void* d_out, int out_size, void* d_ws, size_t ws_size,
                              hipStream_t stream)
{
    const float* x         = (const float*)d_in[0];
    const float* in_proj_w = (const float*)d_in[1];
    const float* conv_w    = (const float*)d_in[2];
    const float* conv_b    = (const float*)d_in[3];
    const float* x_proj_w  = (const float*)d_in[4];
    const float* dt_proj_w = (const float*)d_in[5];
    const float* dt_proj_b = (const float*)d_in[6];
    const float* A_log_re  = (const float*)d_in[7];
    const float* A_log_im  = (const float*)d_in[8];
    const float* Dvec      = (const float*)d_in[9];
    const float* out_proj_w= (const float*)d_in[10];
    float* out = (float*)d_out;

    float* ws    = (float*)d_ws;
    float* xz    = ws;                                        // 4,194,304 f
    float* u     = xz    + (size_t)L_SEQ * 2 * DINNER;        // 2,097,152 f
    float* ssm   = u     + (size_t)L_SEQ * DINNER;            // 2,162,688 f
    float* delta = ssm   + (size_t)L_SEQ * NPROJ;             // 2,097,152 f
    float2* Pc   = (float2*)(delta + (size_t)L_SEQ * DINNER); // 1,048,576 f
    float2* Sc   = Pc + (size_t)NCHUNK * NDN;                 // 1,048,576 f
    float* part  = (float*)(Sc + (size_t)NCHUNK * NDN);       // 8,650,752 f
    unsigned short* uh = (unsigned short*)(part + (size_t)4 * L_SEQ * NPROJ);
    unsigned short* ul = uh + (size_t)L_SEQ * DINNER;
    unsigned short* sh = ul + (size_t)L_SEQ * DINNER;
    unsigned short* sl = sh + (size_t)L_SEQ * DINNER;
    unsigned short* yh = sl + (size_t)L_SEQ * DINNER;
    unsigned short* yl = yh + (size_t)L_SEQ * DINNER;
    // Extended region (weight/x pre-split planes)
    unsigned short* xh  = yl  + (size_t)L_SEQ * DINNER;       // 1,048,576 us each
    unsigned short* xl  = xh  + (size_t)L_SEQ * DMODEL;
    unsigned short* w1h = xl  + (size_t)L_SEQ * DMODEL;       // 4,194,304 us each
    unsigned short* w1l = w1h + (size_t)2 * DINNER * DMODEL;
    unsigned short* w3h = w1l + (size_t)2 * DINNER * DMODEL;  // 4,325,376 us each
    unsigned short* w3l = w3h + (size_t)NPROJ * DINNER;
    unsigned short* w4h = w3l + (size_t)NPROJ * DINNER;       // 4,194,304 us each
    unsigned short* w4l = w4h + (size_t)DINNER * DINNER;
    unsigned short* w6h = w4l + (size_t)DINNER * DINNER;      // 2,097,152 us each
    unsigned short* w6l = w6h + (size_t)DMODEL * DINNER;
    const size_t NEED = ((size_t)(w6l + (size_t)DMODEL * DINNER - (unsigned short*)ws)) * 2;

    const bool pre = (ws_size >= NEED);

    if (pre) {
        // ---- prep: split x + all 4 weights into bf16 hi/lo planes ----
        split_kernel<<<(L_SEQ * DMODEL) / 1024, 256, 0, stream>>>(x, xh, xl);
        split_kernel<<<(2 * DINNER * DMODEL) / 1024, 256, 0, stream>>>(in_proj_w, w1h, w1l);
        split_kernel<<<(NPROJ * DINNER) / 1024, 256, 0, stream>>>(x_proj_w, w3h, w3l);
        split_kernel<<<(DINNER * DINNER) / 1024, 256, 0, stream>>>(dt_proj_w, w4h, w4l);
        split_kernel<<<(DMODEL * DINNER) / 1024, 256, 0, stream>>>(out_proj_w, w6h, w6l);

        // 1) xz = x @ in_proj_w.T   (K=1024, SK=2)
        gemm_bf16ab_sk<128><<<dim3((2 * DINNER) / 64, L_SEQ / 128, 2), 256, 0, stream>>>(
            xh, xl, w1h, w1l, part, L_SEQ, 2 * DINNER, DMODEL);
    } else {
        gemm_mfma_sk<128><<<dim3((2 * DINNER) / 64, L_SEQ / 128, 2), 256, 0, stream>>>(
            x, in_proj_w, part, L_SEQ, 2 * DINNER, DMODEL, DMODEL);
    }
    reduce_splitk<0, 0><<<(L_SEQ * 2 * DINNER) / 1024, 256, 0, stream>>>(
        part, xz, nullptr, nullptr, nullptr, L_SEQ * 2 * DINNER, 2 * DINNER, 2);

    // 2) conv + SiLU -> u (f32) + uh/ul (bf16 split)
    conv_silu_kernel<<<(L_SEQ * DINNER) / 256, 256, 0, stream>>>(
        xz, conv_w, conv_b, u, uh, ul);

    // 3) ssm = u @ x_proj_w.T   (K=2048, SK=4)
    if (pre) {
        gemm_bf16ab_sk<128><<<dim3(NPROJ / 64, L_SEQ / 128, 4), 256, 0, stream>>>(
            uh, ul, w3h, w3l, part, L_SEQ, NPROJ, DINNER);
    } else {
        gemm_bf16a_sk<128><<<dim3(NPROJ / 64, L_SEQ / 128, 4), 256, 0, stream>>>(
            uh, ul, x_proj_w, part, L_SEQ, NPROJ, DINNER);
    }
    reduce_splitk<0, 1><<<(L_SEQ * NPROJ) / 1024, 256, 0, stream>>>(
        part, ssm, nullptr, sh, sl, L_SEQ * NPROJ, NPROJ, 4);

    // 4) delta = softplus(ssm[:, :2048] @ dt_proj_w.T + dt_proj_b)  (SK=4)
    if (pre) {
        gemm_bf16ab_sk<128><<<dim3(DINNER / 64, L_SEQ / 128, 4), 256, 0, stream>>>(
            sh, sl, w4h, w4l, part, L_SEQ, DINNER, DINNER);
    } else {
        gemm_bf16a_sk<128><<<dim3(DINNER / 64, L_SEQ / 128, 4), 256, 0, stream>>>(
            sh, sl, dt_proj_w, part, L_SEQ, DINNER, DINNER);
    }
    reduce_splitk<1, 0><<<(L_SEQ * DINNER) / 1024, 256, 0, stream>>>(
        part, delta, dt_proj_b, nullptr, nullptr, L_SEQ * DINNER, DINNER, 4);

    // 5) chunk-parallel complex scan -> yh/yl
    scan_chunk_kernel<<<(DINNER / 4) * NCHUNK, 64, 0, stream>>>(
        delta, ssm, u, A_log_re, A_log_im, Pc, Sc);
    scan_combine_kernel<<<NDN / 256, 256, 0, stream>>>(Pc, Sc);
    scan_final_kernel<<<(DINNER / 4) * NCHUNK, 64, 0, stream>>>(
        delta, ssm, u, xz, A_log_re, A_log_im, Dvec, Pc, yh, yl);

    // 6) out = y @ out_proj_w.T  (K=2048, BM=64, SK=4)
    if (pre) {
        gemm_bf16ab_sk<64><<<dim3(DMODEL / 64, L_SEQ / 64, 4), 256, 0, stream>>>(
            yh, yl, w6h, w6l, part, L_SEQ, DMODEL, DINNER);
    } else {
        gemm_bf16a_sk<64><<<dim3(DMODEL / 64, L_SEQ / 64, 4), 256, 0, stream>>>(
            yh, yl, out_proj_w, part, L_SEQ, DMODEL, DINNER);
    }
    reduce_splitk<0, 0><<<(L_SEQ * DMODEL) / 1024, 256, 0, stream>>>(
        part, out, nullptr, nullptr, nullptr, L_SEQ * DMODEL, DMODEL, 4);
}